// Round 1
// baseline (43.859 us; speedup 1.0000x reference)
//
#include <hip/hip_runtime.h>
#include <math.h>

#define NQ 10          // qubits
#define NM 16          // 1024 amplitudes / 64 lanes = 16 per lane

// One wave per batch element. Lane l holds amplitudes k = m*64 + l, m=0..15.
// Wire j <-> bit position p = 9-j of k (wire 0 = MSB).
//   p >= 6  -> pair partner differs in m (in-register update)
//   p <  6  -> pair partner differs in lane (shfl_xor)
__global__ __launch_bounds__(256) void qlayer_kernel(
    const float* __restrict__ x,    // [B,10]
    const float* __restrict__ w1,   // [3,1,10,3]
    const float* __restrict__ w2,   // [1,10,3]
    float* __restrict__ out,        // [B,10]
    int B)
{
    const int lane = threadIdx.x & 63;
    const int b = (blockIdx.x << 2) + (threadIdx.x >> 6);  // 4 waves/block
    if (b >= B) return;

    // ---- load x row ----
    float xv[NQ];
#pragma unroll
    for (int j = 0; j < NQ; ++j) xv[j] = x[b * NQ + j];

    float S = 0.f;
#pragma unroll
    for (int j = 0; j < NQ; ++j) S += xv[j];

    // data-reupload phase: angle(k) = -0.5 * sum_j xv[j]*(1-2*bit_j(k))
    //                               = -0.5*S + sum_{bits set in k} xv[wire(bit)]
    // split into lane part (bits 0..5 -> wires 9..4) and m part (bits 6..9 -> wires 3..0)
    float Tlo = 0.f;
#pragma unroll
    for (int p = 0; p < 6; ++p) Tlo += ((lane >> p) & 1) ? xv[9 - p] : 0.f;

    float Thi[NM];
#pragma unroll
    for (int m = 0; m < NM; ++m) {
        float t = 0.f;
#pragma unroll
        for (int q = 0; q < 4; ++q)           // bit p = 6+q -> wire 3-q
            if ((m >> q) & 1) t += xv[3 - q];
        Thi[m] = t;
    }
    const float base = -0.5f * S + Tlo;

    // CZ-ring diagonal sign per k: parity of popcount(k & rotl10(k))
    float czs[NM];
#pragma unroll
    for (int m = 0; m < NM; ++m) {
        const int k  = (m << 6) | lane;
        const int kr = ((k << 1) | (k >> 9)) & 1023;
        czs[m] = (__popc(k & kr) & 1) ? -1.f : 1.f;
    }

    // ---- state |0...0> ----
    float sr[NM], si[NM];
#pragma unroll
    for (int m = 0; m < NM; ++m) { sr[m] = 0.f; si[m] = 0.f; }
    if (lane == 0) sr[0] = 1.f;

    // ---- 4 Rot layers (3 entangling + 1 final); keep L-loop rolled for I-cache ----
#pragma unroll 1
    for (int L = 0; L < 4; ++L) {
        const float* wbase = (L < 3) ? (w1 + L * NQ * 3) : w2;
#pragma unroll
        for (int j = 0; j < NQ; ++j) {
            const float phi   = wbase[j * 3 + 0];
            const float theta = wbase[j * 3 + 1];
            const float omega = wbase[j * 3 + 2];
            float ct, st, epr, epi, emr, emi;
            __sincosf(0.5f * theta, &st, &ct);
            __sincosf(-0.5f * (phi + omega), &epi, &epr);  // ep = exp(-0.5i(phi+omega))
            __sincosf(-0.5f * (phi - omega), &emi, &emr);  // em = exp(-0.5i(phi-omega))
            // M = [[ep*c, -conj(em)*s], [em*s, conj(ep)*c]]
            const float M00r =  epr * ct, M00i =  epi * ct;
            const float M01r = -emr * st, M01i =  emi * st;
            const float M10r =  emr * st, M10i =  emi * st;
            const float M11r =  epr * ct, M11i = -epi * ct;

            const int p = 9 - j;
            if (p >= 6) {
                // in-register pairs: m0 (bit clear) <-> m1 = m0 | (1<<(p-6))
                const int mb = 1 << (p - 6);
#pragma unroll
                for (int m0 = 0; m0 < NM; ++m0) {
                    if (m0 & mb) continue;
                    const int m1 = m0 | mb;
                    const float a0r = sr[m0], a0i = si[m0];
                    const float a1r = sr[m1], a1i = si[m1];
                    sr[m0] = M00r*a0r - M00i*a0i + M01r*a1r - M01i*a1i;
                    si[m0] = M00r*a0i + M00i*a0r + M01r*a1i + M01i*a1r;
                    sr[m1] = M10r*a0r - M10i*a0i + M11r*a1r - M11i*a1i;
                    si[m1] = M10r*a0i + M10i*a0r + M11r*a1i + M11i*a1r;
                }
            } else {
                // cross-lane pairs: partner lane = lane ^ (1<<p)
                const int  msk = 1 << p;
                const bool hi  = (lane >> p) & 1;
                const float c0r = hi ? M10r : M00r, c0i = hi ? M10i : M00i;
                const float c1r = hi ? M11r : M01r, c1i = hi ? M11i : M01i;
#pragma unroll
                for (int m = 0; m < NM; ++m) {
                    const float qr = __shfl_xor(sr[m], msk, 64);
                    const float qi = __shfl_xor(si[m], msk, 64);
                    const float a0r = hi ? qr : sr[m], a0i = hi ? qi : si[m];
                    const float a1r = hi ? sr[m] : qr, a1i = hi ? si[m] : qi;
                    sr[m] = c0r*a0r - c0i*a0i + c1r*a1r - c1i*a1i;
                    si[m] = c0r*a0i + c0i*a0r + c1r*a1i + c1i*a1r;
                }
            }
        }
        // diagonal: CZ ring, plus data-reupload phase for the 3 entangling layers
        if (L < 3) {
#pragma unroll
            for (int m = 0; m < NM; ++m) {
                const float ang = base + Thi[m];
                float sn, cn;
                __sincosf(ang, &sn, &cn);
                const float r = sr[m], ii = si[m];
                sr[m] = (r * cn - ii * sn) * czs[m];
                si[m] = (r * sn + ii * cn) * czs[m];
            }
        } else {
#pragma unroll
            for (int m = 0; m < NM; ++m) { sr[m] *= czs[m]; si[m] *= czs[m]; }
        }
    }

    // ---- expectation values <Z_j> = sum_k |psi_k|^2 * (1-2*bit_j(k)) ----
    float acc[NQ];
#pragma unroll
    for (int j = 0; j < NQ; ++j) acc[j] = 0.f;
#pragma unroll
    for (int m = 0; m < NM; ++m) {
        const float pk = sr[m]*sr[m] + si[m]*si[m];
        const int k = (m << 6) | lane;
#pragma unroll
        for (int j = 0; j < NQ; ++j)
            acc[j] += ((k >> (9 - j)) & 1) ? -pk : pk;
    }
#pragma unroll
    for (int j = 0; j < NQ; ++j) {
        float v = acc[j];
#pragma unroll
        for (int d = 32; d > 0; d >>= 1) v += __shfl_xor(v, d, 64);
        if (lane == 0) out[b * NQ + j] = v;
    }
}

extern "C" void kernel_launch(void* const* d_in, const int* in_sizes, int n_in,
                              void* d_out, int out_size, void* d_ws, size_t ws_size,
                              hipStream_t stream) {
    const float* x  = (const float*)d_in[0];   // [B,10] f32
    const float* w1 = (const float*)d_in[1];   // [3,1,10,3] f32
    const float* w2 = (const float*)d_in[2];   // [1,10,3] f32
    float* out = (float*)d_out;                // [B,10] f32
    const int B = in_sizes[0] / NQ;
    const int blocks = (B + 3) / 4;            // 4 waves (batch elems) per 256-thread block
    qlayer_kernel<<<blocks, 256, 0, stream>>>(x, w1, w2, out, B);
}